// Round 11
// baseline (15.023 us; speedup 1.0000x reference)
//
#include <hip/hip_runtime.h>
#include <math.h>

#define D    512
#define NW   4                             // waves per block
#define NIT  2                             // items per wave, pipelined
#define SWZU(u) ((u) ^ ((((u) >> 4) & 3) << 2))   // bank swizzle on b64 units

typedef __fp16 h8  __attribute__((ext_vector_type(8)));
typedef __fp16 h2  __attribute__((ext_vector_type(2)));
typedef float  f4_ __attribute__((ext_vector_type(4)));

__device__ __forceinline__ h2 cvt2(float lo, float hi) {
    return __builtin_amdgcn_cvt_pkrtz(lo, hi);
}
__device__ __forceinline__ unsigned pk(h2 v) { return __builtin_bit_cast(unsigned, v); }
__device__ __forceinline__ unsigned ab16(unsigned hi, unsigned lo) {
    return __builtin_amdgcn_alignbit(hi, lo, 16);   // (lo.hi16, hi.lo16)
}

// gather one entity row pair (w+b), pack to f16: lane's elements [8l, 8l+8)
__device__ __forceinline__ uint4 gather_row(const float* __restrict__ tw,
                                            const float* __restrict__ tb,
                                            int row, int l)
{
    const float4* w4 = (const float4*)(tw + (size_t)row * D);
    const float4* b4 = (const float4*)(tb + (size_t)row * D);
    float4 a0 = w4[2*l], a1 = w4[2*l+1], a2 = b4[2*l], a3 = b4[2*l+1];
    uint4 v;
    v.x = pk(cvt2(a0.x+a2.x, a0.y+a2.y)); v.y = pk(cvt2(a0.z+a2.z, a0.w+a2.w));
    v.z = pk(cvt2(a1.x+a3.x, a1.y+a3.y)); v.w = pk(cvt2(a1.z+a3.z, a1.w+a3.w));
    return v;
}

// stage: bb doubled+swizzled; 4 shifted a-copies (+wrap tails)
__device__ __forceinline__ void stage_item(uint4* __restrict__ S, int l,
                                           uint4 vb, uint4 va)
{
    const int s0 = SWZU(2*l) >> 1;         // SWZU preserves pair adjacency
    S[s0]      = vb;                       // SWZU(u+128) = SWZU(u)+128
    S[s0 + 64] = vb;

    const unsigned nx1 = (unsigned)__shfl((int)va.x, (l + 1) & 63, 64); // a[8l+8,9]
    const unsigned nx2 = (unsigned)__shfl((int)va.y, (l + 1) & 63, 64); // a[8l+10,11]
    uint4 c1, c2, c3;                      // copy_c[i] = a[(i+c) mod 512]
    c1.x = ab16(va.y, va.x); c1.y = ab16(va.z, va.y);
    c1.z = ab16(va.w, va.z); c1.w = ab16(nx1,  va.w);
    c2.x = va.y; c2.y = va.z; c2.z = va.w; c2.w = nx1;
    c3.x = ab16(va.z, va.y); c3.y = ab16(va.w, va.z);
    c3.z = ab16(nx1,  va.w); c3.w = ab16(nx2,  nx1);
    S[128 + l]       = va;
    S[128 + 66 + l]  = c1;
    S[128 + 132 + l] = c2;
    S[128 + 198 + l] = c3;
    if (l < 2) {                           // wrap tails
        S[128 + 64 + l]       = va;
        S[128 + 66 + 64 + l]  = c1;
        S[128 + 132 + 64 + l] = c2;
        S[128 + 198 + 64 + l] = c3;
    }
}

// 16 iters of 16x16x32 f16 MFMA, two 16x16 shift-tiles
// A[m,k] = bb[512 + k - 16m - 256*tile]; B[k,n] = a[(k+n) mod 512]
__device__ __forceinline__ void mfma_item(const uint4* __restrict__ S,
                                          int mn, int hq, f4_& acc0, f4_& acc1)
{
    const uint2* W = (const uint2*)S;      // b64 units; bb = [0..255]
    int lu = 128 + hq - 4 * mn;            // tile0 logical unit (h0); tile1 = -64
    int ub = 256 + 132 * (mn & 3) + hq + (mn >> 2);   // a-copy b64 base

    acc0 = (f4_){0.f, 0.f, 0.f, 0.f};
    acc1 = (f4_){0.f, 0.f, 0.f, 0.f};

    #pragma unroll
    for (int t = 0; t < 16; ++t) {
        const int s0 = SWZU(lu), s1 = SWZU(lu + 4);
        const uint2 p00 = W[s0],      p01 = W[s1];        // tile0 h0,h1
        const uint2 p10 = W[s0 - 64], p11 = W[s1 - 64];   // tile1 h0,h1
        const uint2 q0  = W[ub],      q1  = W[ub + 4];    // B h0,h1

        const h8 af0 = __builtin_bit_cast(h8, make_uint4(p00.x, p00.y, p01.x, p01.y));
        const h8 af1 = __builtin_bit_cast(h8, make_uint4(p10.x, p10.y, p11.x, p11.y));
        const h8 bf  = __builtin_bit_cast(h8, make_uint4(q0.x,  q0.y,  q1.x,  q1.y));

        acc0 = __builtin_amdgcn_mfma_f32_16x16x32_f16(af0, bf, acc0, 0, 0, 0);
        acc1 = __builtin_amdgcn_mfma_f32_16x16x32_f16(af1, bf, acc1, 0, 0, 0);

        lu += 8; ub += 8;
    }
}

__global__ __launch_bounds__(NW * 64, 4) void hole_mfma_kernel(
    const float* __restrict__ ew, const float* __restrict__ eb,
    const float* __restrict__ rw, const float* __restrict__ rb,
    const int* __restrict__ xs, const int* __restrict__ ys,
    const int* __restrict__ rs, float* __restrict__ out)
{
    // per wave (uint4 slots): [0..127] bb doubled (unit-swizzled);
    // [128+66c .. +65] a-copy shifted by c, c=0..3 (reused across both items)
    __shared__ uint4 smem[NW][392];

    const int w  = threadIdx.x >> 6;
    const int l  = threadIdx.x & 63;
    const int mn = l & 15;                 // MFMA row m (A) == col n (B)
    const int hq = l >> 4;                 // k-group selector
    const int i0 = (blockIdx.x * NW + w) * NIT;

    const int x0 = xs[i0],   y0 = ys[i0],   r0 = rs[i0];
    const int x1 = xs[i0+1], y1 = ys[i0+1], r1 = rs[i0+1];

    uint4* S = smem[w];
    const int ridx = 64 * hq + mn;
    const float* rw0 = rw + (size_t)r0 * D, *rb0 = rb + (size_t)r0 * D;
    const float* rw1 = rw + (size_t)r1 * D, *rb1 = rb + (size_t)r1 * D;

    // ---- item0 gather + stage ----
    const uint4 vb0 = gather_row(ew, eb, y0, l);
    const uint4 va0 = gather_row(ew, eb, x0, l);
    stage_item(S, l, vb0, va0);

    // ---- issue item1 gather + item0 rel NOW (latency hides under MFMA0) ----
    const uint4 vb1 = gather_row(ew, eb, y1, l);
    const uint4 va1 = gather_row(ew, eb, x1, l);
    float rv0[8];
    #pragma unroll
    for (int q = 0; q < 4; ++q) {
        rv0[q]   = rw0[ridx + 16*q]       + rb0[ridx + 16*q];
        rv0[4+q] = rw0[ridx + 16*q + 256] + rb0[ridx + 16*q + 256];
    }

    // ---- MFMA item0 ----
    f4_ acc0, acc1;
    mfma_item(S, mn, hq, acc0, acc1);

    // ---- epilogue item0 ----
    {
        float part = acc0[0]*rv0[0] + acc0[1]*rv0[1] + acc0[2]*rv0[2] + acc0[3]*rv0[3]
                   + acc1[0]*rv0[4] + acc1[1]*rv0[5] + acc1[2]*rv0[6] + acc1[3]*rv0[7];
        #pragma unroll
        for (int off = 32; off >= 1; off >>= 1) part += __shfl_down(part, off, 64);
        if (l == 0) out[i0] = 1.0f / (1.0f + expf(-part * (1.0f / (float)D)));
    }

    // ---- stage item1 (lgkmcnt orders writes after MFMA0's LDS reads) ----
    stage_item(S, l, vb1, va1);

    float rv1[8];
    #pragma unroll
    for (int q = 0; q < 4; ++q) {
        rv1[q]   = rw1[ridx + 16*q]       + rb1[ridx + 16*q];
        rv1[4+q] = rw1[ridx + 16*q + 256] + rb1[ridx + 16*q + 256];
    }

    // ---- MFMA item1 + epilogue ----
    mfma_item(S, mn, hq, acc0, acc1);
    {
        float part = acc0[0]*rv1[0] + acc0[1]*rv1[1] + acc0[2]*rv1[2] + acc0[3]*rv1[3]
                   + acc1[0]*rv1[4] + acc1[1]*rv1[5] + acc1[2]*rv1[6] + acc1[3]*rv1[7];
        #pragma unroll
        for (int off = 32; off >= 1; off >>= 1) part += __shfl_down(part, off, 64);
        if (l == 0) out[i0+1] = 1.0f / (1.0f + expf(-part * (1.0f / (float)D)));
    }
}

extern "C" void kernel_launch(void* const* d_in, const int* in_sizes, int n_in,
                              void* d_out, int out_size, void* d_ws, size_t ws_size,
                              hipStream_t stream)
{
    const float* ew = (const float*)d_in[0];
    const float* eb = (const float*)d_in[1];
    const float* rw = (const float*)d_in[2];
    const float* rb = (const float*)d_in[3];
    const int*   xs = (const int*)d_in[4];
    const int*   ys = (const int*)d_in[5];
    const int*   rs = (const int*)d_in[6];
    float* out = (float*)d_out;

    const int batch = in_sizes[4];                    // 4096
    dim3 grid(batch / (NW * NIT)), block(NW * 64);    // 512 x 256
    hole_mfma_kernel<<<grid, block, 0, stream>>>(ew, eb, rw, rb, xs, ys, rs, out);
}